// Round 13
// baseline (280.082 us; speedup 1.0000x reference)
//
#include <hip/hip_runtime.h>
#include <hip/hip_bf16.h>
#include <cstdint>

// Problem constants (LongformerSelfAttention: B=2, S=2048, M=768, H=12, D=64, W=256, DIL=1)
#define SEQ    2048
#define HIDDEN 768
#define NHEAD  12
#define HDIM   64
#define WIN    256
#define BATCH  2
#define MTOT   (BATCH * SEQ)   // 4096 tokens

typedef __attribute__((ext_vector_type(8))) short short8;   // 8 bf16 = 4 VGPR (MFMA A/B frag)
typedef __attribute__((ext_vector_type(4))) float f32x4;    // MFMA C/D frag

union S8U4 { short8 s; uint4 u; };

// ---------------------------------------------------------------------------
// Pair-wise fp32 -> (hi, lo) bf16 split using v_cvt_pk_bf16_f32 (RNE).
// ---------------------------------------------------------------------------
__device__ __forceinline__ void bf16_split2(float a, float b, uint& h2, uint& l2) {
    union { __hip_bfloat162 v; uint u; } ch, cl;
    ch.v = __float22bfloat162_rn(make_float2(a, b));
    float af = __uint_as_float(ch.u << 16);           // hi(a) as f32
    float bf = __uint_as_float(ch.u & 0xFFFF0000u);   // hi(b) as f32
    cl.v = __float22bfloat162_rn(make_float2(a - af, b - bf));
    h2 = ch.u;
    l2 = cl.u;
}

// ---------------------------------------------------------------------------
// Projection GEMM via split-bf16 MFMA (R12 structure) + T14 async-STAGE:
// next k-tile's global loads are issued into REGISTERS before the barrier
// (latency hides under current tile's MFMA/conversion); convert + LDS-write
// happen after the post-MFMA barrier. R12's serial chain
// {barrier -> load -> convert -> write -> barrier -> MFMA} exposed ~500cy
// of load latency per k-iter (proj VALUBusy 35%, no pipe saturated).
// fp32 outputs [bh][s][d], 64B-segment stores (WRITE 36.8 MB, clean).
// ---------------------------------------------------------------------------
__global__ __launch_bounds__(256) void proj_mfma_kernel(
    const float* __restrict__ X,
    const float* __restrict__ Wq, const float* __restrict__ bq,
    const float* __restrict__ Wk, const float* __restrict__ bk,
    const float* __restrict__ Wv, const float* __restrict__ bv,
    float* __restrict__ Qo, float* __restrict__ Ko, float* __restrict__ Vo)
{
    const int which = blockIdx.z;
    const float* __restrict__ W    = (which == 0) ? Wq : (which == 1) ? Wk : Wv;
    const float* __restrict__ bias = (which == 0) ? bq : (which == 1) ? bk : bv;
    float* __restrict__ out        = (which == 0) ? Qo : (which == 1) ? Ko : Vo;
    const float scale = (which == 0) ? 0.125f : 1.0f;

    __shared__ __align__(16) ushort Ahi[128 * 64];
    __shared__ __align__(16) ushort Alo[128 * 64];
    __shared__ __align__(16) ushort Bhi[64 * 64];
    __shared__ __align__(16) ushort Blo[64 * 64];

    const int t  = threadIdx.x;
    const int m0 = blockIdx.x * 128;
    const int h  = blockIdx.y;
    const int n0 = h * 64;

    const int w    = t >> 6;
    const int lane = t & 63;
    const int wr   = w >> 1;
    const int wc   = w & 1;
    const int lr   = lane & 15;
    const int lk   = lane >> 4;

    // staging geometry: thread covers A rows {srow+32i} x chunk sc4 (4 floats)
    const int srow = t >> 4;          // 0..15
    const int sc4  = t & 15;          // float4 column 0..15

    float4 a_f4[8], b_f4[4];

    auto LOADT = [&](int k0) {
#pragma unroll
        for (int i = 0; i < 8; ++i) {          // A: 128 rows
            int row = srow + i * 16;
            a_f4[i] = *(const float4*)&X[(size_t)(m0 + row) * HIDDEN + k0 + sc4 * 4];
        }
#pragma unroll
        for (int i = 0; i < 4; ++i) {          // B: 64 rows
            int row = srow + i * 16;
            b_f4[i] = *(const float4*)&W[(size_t)(n0 + row) * HIDDEN + k0 + sc4 * 4];
        }
    };
    auto STORET = [&]() {
#pragma unroll
        for (int i = 0; i < 8; ++i) {
            int row = srow + i * 16;
            uint h01, l01, h23, l23;
            bf16_split2(a_f4[i].x, a_f4[i].y, h01, l01);
            bf16_split2(a_f4[i].z, a_f4[i].w, h23, l23);
            int idx = (row * 64 + sc4 * 4) ^ ((row & 7) << 3);
            *(uint2*)&Ahi[idx] = make_uint2(h01, h23);
            *(uint2*)&Alo[idx] = make_uint2(l01, l23);
        }
#pragma unroll
        for (int i = 0; i < 4; ++i) {
            int row = srow + i * 16;
            uint h01, l01, h23, l23;
            bf16_split2(b_f4[i].x, b_f4[i].y, h01, l01);
            bf16_split2(b_f4[i].z, b_f4[i].w, h23, l23);
            int idx = (row * 64 + sc4 * 4) ^ ((row & 7) << 3);
            *(uint2*)&Bhi[idx] = make_uint2(h01, h23);
            *(uint2*)&Blo[idx] = make_uint2(l01, l23);
        }
    };

    f32x4 acc[4][2];
#pragma unroll
    for (int i = 0; i < 4; ++i)
#pragma unroll
        for (int j = 0; j < 2; ++j) acc[i][j] = (f32x4){0.f, 0.f, 0.f, 0.f};

    LOADT(0);
    STORET();                                   // preload k-tile 0

    for (int k0 = 0; k0 < HIDDEN; k0 += 64) {
        const bool more = (k0 + 64) < HIDDEN;
        if (more) LOADT(k0 + 64);               // T14: issue early
        __syncthreads();                        // staged tile visible

#pragma unroll
        for (int s = 0; s < 2; ++s) {
            short8 ah[4], al[4], bh2[2], bl2[2];
#pragma unroll
            for (int fm = 0; fm < 4; ++fm) {
                int row = wr * 64 + fm * 16 + lr;
                int idx = (row * 64 + s * 32 + lk * 8) ^ ((row & 7) << 3);
                ah[fm] = *(const short8*)&Ahi[idx];
                al[fm] = *(const short8*)&Alo[idx];
            }
#pragma unroll
            for (int fn = 0; fn < 2; ++fn) {
                int row = wc * 32 + fn * 16 + lr;
                int idx = (row * 64 + s * 32 + lk * 8) ^ ((row & 7) << 3);
                bh2[fn] = *(const short8*)&Bhi[idx];
                bl2[fn] = *(const short8*)&Blo[idx];
            }
#pragma unroll
            for (int fm = 0; fm < 4; ++fm)
#pragma unroll
                for (int fn = 0; fn < 2; ++fn) {
                    acc[fm][fn] = __builtin_amdgcn_mfma_f32_16x16x32_bf16(
                        ah[fm], bh2[fn], acc[fm][fn], 0, 0, 0);
                    acc[fm][fn] = __builtin_amdgcn_mfma_f32_16x16x32_bf16(
                        ah[fm], bl2[fn], acc[fm][fn], 0, 0, 0);
                    acc[fm][fn] = __builtin_amdgcn_mfma_f32_16x16x32_bf16(
                        al[fm], bh2[fn], acc[fm][fn], 0, 0, 0);
                }
        }

        __syncthreads();                        // all frag reads done
        if (more) STORET();                     // convert + commit next tile
    }

    // ---- epilogue: fp32 stores, 64B contiguous per 16-lane group ----
#pragma unroll
    for (int fn = 0; fn < 2; ++fn) {
        int d = wc * 32 + fn * 16 + lr;
        float bval = bias[n0 + d];
#pragma unroll
        for (int fm = 0; fm < 4; ++fm) {
#pragma unroll
            for (int r = 0; r < 4; ++r) {
                int m  = m0 + wr * 64 + fm * 16 + lk * 4 + r;
                int bb = m >> 11;
                int ss = m & (SEQ - 1);
                out[(((size_t)(bb * NHEAD + h) * SEQ) + ss) * HDIM + d] =
                    (acc[fm][fn][r] + bval) * scale;
            }
        }
    }
}

// ---------------------------------------------------------------------------
// Prefix sum of V along sequence per (b,h,d). 1024 threads: 16 chunks of 128
// (R12's 4x512 serial chains on 24 blocks were pure latency).
// ---------------------------------------------------------------------------
__global__ __launch_bounds__(1024) void vprefix_kernel(
    const float* __restrict__ V, float* __restrict__ Vpre)
{
    const int bh    = blockIdx.x;
    const int d     = threadIdx.x & 63;
    const int chunk = threadIdx.x >> 6;   // 0..15
    const float* vb = &V[(size_t)bh * SEQ * HDIM];
    float* pb       = &Vpre[(size_t)bh * SEQ * HDIM];

    __shared__ float csum[16][64];
    const int s0 = chunk * 128;
    float sum = 0.f;
    for (int s = s0; s < s0 + 128; ++s) sum += vb[(size_t)s * HDIM + d];
    csum[chunk][d] = sum;
    __syncthreads();
    float run = 0.f;
    for (int c = 0; c < chunk; ++c) run += csum[c][d];
    for (int s = s0; s < s0 + 128; ++s) {
        run += vb[(size_t)s * HDIM + d];
        pb[(size_t)s * HDIM + d] = run;
    }
}

// ---------------------------------------------------------------------------
// Banded attention (R12 verbatim — QBLK=128, 512 threads, 8 waves; split-bf16
// MFMA, swapped operands, lane-local softmax, Vpre mask correction, cvt_pk).
// ---------------------------------------------------------------------------
__global__ __launch_bounds__(512, 2) void attn_kernel(
    const float* __restrict__ Q, const float* __restrict__ K,
    const float* __restrict__ V, const float* __restrict__ Vpre,
    float* __restrict__ out)
{
    __shared__ __align__(16) ushort Khi[64 * 64], Klo[64 * 64];   // [key][d] ^((key&7)<<3)
    __shared__ __align__(16) ushort VThi[64 * 64], VTlo[64 * 64]; // [d][key] ^((d&7)<<3)
    __shared__ __align__(16) ushort Phi_s[8][16 * 64];            // per-wave [q][key] ^((q&7)<<3)
    __shared__ __align__(16) ushort Plo_s[8][16 * 64];

    const int t    = threadIdx.x;
    const int lane = t & 63;
    const int wv   = t >> 6;                   // wave 0..7 -> q rows wv*16..+15
    const int l15  = lane & 15;
    const int g2   = lane >> 4;                // 0..3

    const int L    = blockIdx.x;               // 384 blocks
    const int xcd  = L & 7;
    const int slot = L >> 3;                   // 0..47
    const int bh   = xcd * 3 + (slot >> 4);    // 0..23
    const int qb   = slot & 15;                // 0..15
    const int b    = bh / NHEAD;
    const int h    = bh % NHEAD;
    const int i0   = qb * 128;
    const int i    = i0 + wv * 16 + l15;       // this lane's q row (acc column)

    const float* kbase = &K[(size_t)bh * SEQ * HDIM];
    const float* vbase = &V[(size_t)bh * SEQ * HDIM];

    // ---- Q fragments (B-operand), hoisted, hi/lo via cvt_pk ----
    short8 qh[2], qlo[2];
    {
        const float* qrow = &Q[((size_t)bh * SEQ + i) * HDIM];
#pragma unroll
        for (int s = 0; s < 2; ++s) {
            float4 a = *(const float4*)&qrow[s * 32 + g2 * 8];
            float4 c = *(const float4*)&qrow[s * 32 + g2 * 8 + 4];
            S8U4 H, L;
            bf16_split2(a.x, a.y, H.u.x, L.u.x);
            bf16_split2(a.z, a.w, H.u.y, L.u.y);
            bf16_split2(c.x, c.y, H.u.z, L.u.z);
            bf16_split2(c.z, c.w, H.u.w, L.u.w);
            qh[s]  = H.s;
            qlo[s] = L.s;
        }
    }

    // ---- staging assignment (512 threads; 8 K-floats + 8 V-floats each) ----
    const int krow = t >> 3;                   // 0..63 (key row)
    const int kc   = (t & 7) * 8;              // d offset, 8 floats
    const int vkp  = t >> 4;                   // 0..31 -> keys 2vkp, 2vkp+1
    const int vdc  = (t & 15) * 4;             // d offset, 4 floats
    float4 kpre[2], vp0, vp1;

    const int jlo_blk = max(0, i0 - WIN);
    const int jhi_blk = min(SEQ - 1, i0 + 127 + WIN);

    auto LOADT = [&](int jt2) {
        const float* kr = &kbase[(size_t)(jt2 + krow) * HDIM + kc];
        kpre[0] = *(const float4*)&kr[0];
        kpre[1] = *(const float4*)&kr[4];
        vp0 = *(const float4*)&vbase[(size_t)(jt2 + 2 * vkp) * HDIM + vdc];
        vp1 = *(const float4*)&vbase[(size_t)(jt2 + 2 * vkp + 1) * HDIM + vdc];
    };
    auto STORET = [&]() {
#pragma unroll
        for (int c = 0; c < 2; ++c) {
            uint h01, l01, h23, l23;
            bf16_split2(kpre[c].x, kpre[c].y, h01, l01);
            bf16_split2(kpre[c].z, kpre[c].w, h23, l23);
            int idx = (krow * 64 + kc + c * 4) ^ ((krow & 7) << 3);
            *(uint2*)&Khi[idx] = make_uint2(h01, h23);
            *(uint2*)&Klo[idx] = make_uint2(l01, l23);
        }
        float va[4] = {vp0.x, vp0.y, vp0.z, vp0.w};
        float vb4[4] = {vp1.x, vp1.y, vp1.z, vp1.w};
#pragma unroll
        for (int j = 0; j < 4; ++j) {
            int d = vdc + j;
            uint hj, lj;
            bf16_split2(va[j], vb4[j], hj, lj);   // key 2vkp low, 2vkp+1 high
            int idx = (d * 64 + 2 * vkp) ^ ((d & 7) << 3);
            *(uint*)&VThi[idx] = hj;
            *(uint*)&VTlo[idx] = lj;
        }
    };

    float mrun = 0.f, lrun = 0.f;              // mask zeros always in softmax set
    f32x4 ctx[4];
#pragma unroll
    for (int f = 0; f < 4; ++f) ctx[f] = (f32x4){0.f, 0.f, 0.f, 0.f};

    LOADT(jlo_blk);
    STORET();                                   // preload tile 0

    for (int jt = jlo_blk; jt <= jhi_blk; jt += 64) {
        const bool more = (jt + 64) <= jhi_blk;
        if (more) LOADT(jt + 64);               // T14: issue early, write late
        __syncthreads();                        // staged tile visible

        // ---- QK^T: S^T[64 keys][16 q] ----
        f32x4 sacc[4];
#pragma unroll
        for (int f = 0; f < 4; ++f) sacc[f] = (f32x4){0.f, 0.f, 0.f, 0.f};
#pragma unroll
        for (int s = 0; s < 2; ++s) {
            short8 kh[4], kl[4];
#pragma unroll
            for (int f = 0; f < 4; ++f) {
                int row = f * 16 + l15;
                int idx = (row * 64 + s * 32 + g2 * 8) ^ ((row & 7) << 3);
                kh[f] = *(const short8*)&Khi[idx];
                kl[f] = *(const short8*)&Klo[idx];
            }
#pragma unroll
            for (int f = 0; f < 4; ++f) {
                sacc[f] = __builtin_amdgcn_mfma_f32_16x16x32_bf16(kh[f], qh[s],  sacc[f], 0, 0, 0);
                sacc[f] = __builtin_amdgcn_mfma_f32_16x16x32_bf16(kh[f], qlo[s], sacc[f], 0, 0, 0);
                sacc[f] = __builtin_amdgcn_mfma_f32_16x16x32_bf16(kl[f], qh[s],  sacc[f], 0, 0, 0);
            }
        }

        // ---- softmax (lane-local rows; key j = jt + f*16 + g2*4 + r) ----
        float p[4][4];
        float tmax = -1e30f;
#pragma unroll
        for (int f = 0; f < 4; ++f)
#pragma unroll
            for (int r = 0; r < 4; ++r) {
                int j = jt + f * 16 + g2 * 4 + r;
                bool inw = (j >= i - WIN) && (j <= i + WIN);
                float sv_ = inw ? sacc[f][r] : -1e30f;
                p[f][r] = sv_;
                tmax = fmaxf(tmax, sv_);
            }
        tmax = fmaxf(tmax, __shfl_xor(tmax, 16));
        tmax = fmaxf(tmax, __shfl_xor(tmax, 32));
        float m_new = fmaxf(mrun, tmax);
        float resc  = __expf(mrun - m_new);
        float lsum  = 0.f;
#pragma unroll
        for (int f = 0; f < 4; ++f)
#pragma unroll
            for (int r = 0; r < 4; ++r) {
                float pe = __expf(p[f][r] - m_new);
                p[f][r] = pe;
                lsum += pe;
            }
        lsum += __shfl_xor(lsum, 16);
        lsum += __shfl_xor(lsum, 32);
        lrun = lrun * resc + lsum;
        mrun = m_new;
#pragma unroll
        for (int f = 0; f < 4; ++f) {
            ctx[f][0] *= resc; ctx[f][1] *= resc;
            ctx[f][2] *= resc; ctx[f][3] *= resc;
        }

        // ---- P -> bf16 hi/lo into per-wave LDS ([q][key], swizzled) ----
#pragma unroll
        for (int f = 0; f < 4; ++f) {
            uint h01, l01, h23, l23;
            bf16_split2(p[f][0], p[f][1], h01, l01);
            bf16_split2(p[f][2], p[f][3], h23, l23);
            int idx = (l15 * 64 + f * 16 + g2 * 4) ^ ((l15 & 7) << 3);
            *(uint2*)&Phi_s[wv][idx] = make_uint2(h01, h23);
            *(uint2*)&Plo_s[wv][idx] = make_uint2(l01, l23);
        }

        // ---- PV: ctx^T[64 d][16 q] += V^T . P^T ----
#pragma unroll
        for (int s = 0; s < 2; ++s) {
            int pidx = (l15 * 64 + s * 32 + g2 * 8) ^ ((l15 & 7) << 3);
            short8 ph = *(const short8*)&Phi_s[wv][pidx];
            short8 pl = *(const short8*)&Plo_s[wv][pidx];
#pragma unroll
            for (int f = 0; f < 4; ++f) {
                int row = f * 16 + l15;
                int idx = (row * 64 + s * 32 + g2 * 8) ^ ((row & 7) << 3);
                short8 vh = *(const short8*)&VThi[idx];
                short8 vl = *(const short8*)&VTlo[idx];
                ctx[f] = __builtin_amdgcn_mfma_f32_16x16x32_bf16(vh, ph, ctx[f], 0, 0, 0);
                ctx[f] = __builtin_amdgcn_mfma_f32_16x16x32_bf16(vl, ph, ctx[f], 0, 0, 0);
                ctx[f] = __builtin_amdgcn_mfma_f32_16x16x32_bf16(vh, pl, ctx[f], 0, 0, 0);
            }
        }

        __syncthreads();                        // all reads of this tile done
        if (more) STORET();                     // commit prefetched tile
    }

    // ---- out-of-window correction + normalize + store ----
    const int jlo = max(0, i - WIN);
    const int jhi = min(SEQ - 1, i + WIN);
    const int cnt = jhi - jlo + 1;
    const float em   = __expf(-mrun);
    const float ltot = lrun + (float)(SEQ - cnt) * em;
    const float inv  = 1.f / ltot;

    const float* vpT = &Vpre[((size_t)bh * SEQ + (SEQ - 1)) * HDIM];
    const float* vpH = &Vpre[((size_t)bh * SEQ + jhi) * HDIM];
    const float* vpL = &Vpre[((size_t)bh * SEQ + (jlo - 1)) * HDIM];  // read only if jlo>0
    float* orow = &out[((size_t)(b * SEQ + i)) * HIDDEN + h * HDIM];

#pragma unroll
    for (int f = 0; f < 4; ++f) {
        int d0 = f * 16 + g2 * 4;
        float4 tt = *(const float4*)&vpT[d0];
        float4 hh = *(const float4*)&vpH[d0];
        float4 ll = {0.f, 0.f, 0.f, 0.f};
        if (jlo > 0) ll = *(const float4*)&vpL[d0];
        float4 o;
        o.x = (ctx[f][0] + em * (tt.x - hh.x + ll.x)) * inv;
        o.y = (ctx[f][1] + em * (tt.y - hh.y + ll.y)) * inv;
        o.z = (ctx[f][2] + em * (tt.z - hh.z + ll.z)) * inv;
        o.w = (ctx[f][3] + em * (tt.w - hh.w + ll.w)) * inv;
        *(float4*)&orow[d0] = o;
    }
}

// ---------------------------------------------------------------------------
extern "C" void kernel_launch(void* const* d_in, const int* in_sizes, int n_in,
                              void* d_out, int out_size, void* d_ws, size_t ws_size,
                              hipStream_t stream) {
    const float* X  = (const float*)d_in[0];
    const float* Wq = (const float*)d_in[1];
    const float* bq = (const float*)d_in[2];
    const float* Wk = (const float*)d_in[3];
    const float* bk = (const float*)d_in[4];
    const float* Wv = (const float*)d_in[5];
    const float* bv = (const float*)d_in[6];
    float* out = (float*)d_out;

    const size_t TEN = (size_t)BATCH * NHEAD * SEQ * HDIM;  // 3,145,728 floats
    float* qf   = (float*)d_ws;
    float* kf   = qf + TEN;
    float* vf   = kf + TEN;
    float* vpre = vf + TEN;   // 50.3 MB of ws total

    proj_mfma_kernel<<<dim3(MTOT / 128, NHEAD, 3), 256, 0, stream>>>(
        X, Wq, bq, Wk, bk, Wv, bv, qf, kf, vf);
    vprefix_kernel<<<dim3(BATCH * NHEAD), 1024, 0, stream>>>(vf, vpre);
    attn_kernel<<<dim3((SEQ / 128) * BATCH * NHEAD), 512, 0, stream>>>(
        qf, kf, vf, vpre, out);
}

// Round 14
// 223.344 us; speedup vs baseline: 1.2540x; 1.2540x over previous
//
#include <hip/hip_runtime.h>
#include <hip/hip_bf16.h>
#include <cstdint>

// Problem constants (LongformerSelfAttention: B=2, S=2048, M=768, H=12, D=64, W=256, DIL=1)
#define SEQ    2048
#define HIDDEN 768
#define NHEAD  12
#define HDIM   64
#define WIN    256
#define BATCH  2
#define MTOT   (BATCH * SEQ)   // 4096 tokens

typedef __attribute__((ext_vector_type(8))) short short8;   // 8 bf16 = 4 VGPR (MFMA A/B frag)
typedef __attribute__((ext_vector_type(4))) float f32x4;    // MFMA C/D frag

union S8U4 { short8 s; uint4 u; };

// ---------------------------------------------------------------------------
// Pair-wise fp32 -> (hi, lo) bf16 split using v_cvt_pk_bf16_f32 (RNE).
// ---------------------------------------------------------------------------
__device__ __forceinline__ void bf16_split2(float a, float b, uint& h2, uint& l2) {
    union { __hip_bfloat162 v; uint u; } ch, cl;
    ch.v = __float22bfloat162_rn(make_float2(a, b));
    float af = __uint_as_float(ch.u << 16);           // hi(a) as f32
    float bf = __uint_as_float(ch.u & 0xFFFF0000u);   // hi(b) as f32
    cl.v = __float22bfloat162_rn(make_float2(a - af, b - bf));
    h2 = ch.u;
    l2 = cl.u;
}

// ---------------------------------------------------------------------------
// Projection GEMM via split-bf16 MFMA — R12 VERBATIM (proven 88 us).
// R13 lesson: T14 register-prefetch pushed VGPR 112->132, occupancy
// 16.6->10.3%, dur 88->145 us. Wave-level parallelism > intra-wave
// pipelining here. In-loop staging + cvt_pk conversion; fp32 outputs
// [bh][s][d] via 64B-segment stores (WRITE 36.8 MB, clean).
// ---------------------------------------------------------------------------
__global__ __launch_bounds__(256) void proj_mfma_kernel(
    const float* __restrict__ X,
    const float* __restrict__ Wq, const float* __restrict__ bq,
    const float* __restrict__ Wk, const float* __restrict__ bk,
    const float* __restrict__ Wv, const float* __restrict__ bv,
    float* __restrict__ Qo, float* __restrict__ Ko, float* __restrict__ Vo)
{
    const int which = blockIdx.z;
    const float* __restrict__ W    = (which == 0) ? Wq : (which == 1) ? Wk : Wv;
    const float* __restrict__ bias = (which == 0) ? bq : (which == 1) ? bk : bv;
    float* __restrict__ out        = (which == 0) ? Qo : (which == 1) ? Ko : Vo;
    const float scale = (which == 0) ? 0.125f : 1.0f;

    __shared__ __align__(16) ushort Ahi[128 * 64];
    __shared__ __align__(16) ushort Alo[128 * 64];
    __shared__ __align__(16) ushort Bhi[64 * 64];
    __shared__ __align__(16) ushort Blo[64 * 64];

    const int t  = threadIdx.x;
    const int m0 = blockIdx.x * 128;
    const int h  = blockIdx.y;
    const int n0 = h * 64;

    const int w    = t >> 6;
    const int lane = t & 63;
    const int wr   = w >> 1;
    const int wc   = w & 1;
    const int lr   = lane & 15;
    const int lk   = lane >> 4;

    f32x4 acc[4][2];
#pragma unroll
    for (int i = 0; i < 4; ++i)
#pragma unroll
        for (int j = 0; j < 2; ++j) acc[i][j] = (f32x4){0.f, 0.f, 0.f, 0.f};

    for (int k0 = 0; k0 < HIDDEN; k0 += 64) {
        __syncthreads();
#pragma unroll
        for (int i = 0; i < 8; ++i) {
            int id  = t + i * 256;
            int row = id >> 4;
            int c4  = id & 15;
            const float4 xv = *(const float4*)&X[(size_t)(m0 + row) * HIDDEN + k0 + c4 * 4];
            uint h01, l01, h23, l23;
            bf16_split2(xv.x, xv.y, h01, l01);
            bf16_split2(xv.z, xv.w, h23, l23);
            int idx = (row * 64 + c4 * 4) ^ ((row & 7) << 3);
            *(uint2*)&Ahi[idx] = make_uint2(h01, h23);
            *(uint2*)&Alo[idx] = make_uint2(l01, l23);
        }
#pragma unroll
        for (int i = 0; i < 4; ++i) {
            int id  = t + i * 256;
            int row = id >> 4;
            int c4  = id & 15;
            const float4 wv4 = *(const float4*)&W[(size_t)(n0 + row) * HIDDEN + k0 + c4 * 4];
            uint h01, l01, h23, l23;
            bf16_split2(wv4.x, wv4.y, h01, l01);
            bf16_split2(wv4.z, wv4.w, h23, l23);
            int idx = (row * 64 + c4 * 4) ^ ((row & 7) << 3);
            *(uint2*)&Bhi[idx] = make_uint2(h01, h23);
            *(uint2*)&Blo[idx] = make_uint2(l01, l23);
        }
        __syncthreads();

#pragma unroll
        for (int s = 0; s < 2; ++s) {
            short8 ah[4], al[4], bh2[2], bl2[2];
#pragma unroll
            for (int fm = 0; fm < 4; ++fm) {
                int row = wr * 64 + fm * 16 + lr;
                int idx = (row * 64 + s * 32 + lk * 8) ^ ((row & 7) << 3);
                ah[fm] = *(const short8*)&Ahi[idx];
                al[fm] = *(const short8*)&Alo[idx];
            }
#pragma unroll
            for (int fn = 0; fn < 2; ++fn) {
                int row = wc * 32 + fn * 16 + lr;
                int idx = (row * 64 + s * 32 + lk * 8) ^ ((row & 7) << 3);
                bh2[fn] = *(const short8*)&Bhi[idx];
                bl2[fn] = *(const short8*)&Blo[idx];
            }
#pragma unroll
            for (int fm = 0; fm < 4; ++fm)
#pragma unroll
                for (int fn = 0; fn < 2; ++fn) {
                    acc[fm][fn] = __builtin_amdgcn_mfma_f32_16x16x32_bf16(
                        ah[fm], bh2[fn], acc[fm][fn], 0, 0, 0);
                    acc[fm][fn] = __builtin_amdgcn_mfma_f32_16x16x32_bf16(
                        ah[fm], bl2[fn], acc[fm][fn], 0, 0, 0);
                    acc[fm][fn] = __builtin_amdgcn_mfma_f32_16x16x32_bf16(
                        al[fm], bh2[fn], acc[fm][fn], 0, 0, 0);
                }
        }
    }

    // ---- epilogue: fp32 stores, 64B contiguous per 16-lane group ----
#pragma unroll
    for (int fn = 0; fn < 2; ++fn) {
        int d = wc * 32 + fn * 16 + lr;
        float bval = bias[n0 + d];
#pragma unroll
        for (int fm = 0; fm < 4; ++fm) {
#pragma unroll
            for (int r = 0; r < 4; ++r) {
                int m  = m0 + wr * 64 + fm * 16 + lk * 4 + r;
                int bb = m >> 11;
                int ss = m & (SEQ - 1);
                out[(((size_t)(bb * NHEAD + h) * SEQ) + ss) * HDIM + d] =
                    (acc[fm][fn][r] + bval) * scale;
            }
        }
    }
}

// ---------------------------------------------------------------------------
// Prefix sum of V along sequence per (b,h,d). 1024 threads, 16 chunks of 128.
// ---------------------------------------------------------------------------
__global__ __launch_bounds__(1024) void vprefix_kernel(
    const float* __restrict__ V, float* __restrict__ Vpre)
{
    const int bh    = blockIdx.x;
    const int d     = threadIdx.x & 63;
    const int chunk = threadIdx.x >> 6;   // 0..15
    const float* vb = &V[(size_t)bh * SEQ * HDIM];
    float* pb       = &Vpre[(size_t)bh * SEQ * HDIM];

    __shared__ float csum[16][64];
    const int s0 = chunk * 128;
    float sum = 0.f;
    for (int s = s0; s < s0 + 128; ++s) sum += vb[(size_t)s * HDIM + d];
    csum[chunk][d] = sum;
    __syncthreads();
    float run = 0.f;
    for (int c = 0; c < chunk; ++c) run += csum[c][d];
    for (int s = s0; s < s0 + 128; ++s) {
        run += vb[(size_t)s * HDIM + d];
        pb[(size_t)s * HDIM + d] = run;
    }
}

// ---------------------------------------------------------------------------
// Banded attention (R12 structure) + PER-WAVE MASKED-TILE SKIP:
// a wave whose 16 q-rows have no key in [wv_lo-WIN, wv_lo+15+WIN] inside
// the current tile would compute all-masked scores (tmax=-1e30 -> m_new=mrun,
// resc=1, lsum=0, P=0, PV+=0) — skipping the compute section is
// bit-identical. Skip is wave-uniform; both barriers still executed by all.
// Saves ~12-17% of attn compute (10 tiles staged, ~8.5 active per wave).
// ---------------------------------------------------------------------------
__global__ __launch_bounds__(512, 2) void attn_kernel(
    const float* __restrict__ Q, const float* __restrict__ K,
    const float* __restrict__ V, const float* __restrict__ Vpre,
    float* __restrict__ out)
{
    __shared__ __align__(16) ushort Khi[64 * 64], Klo[64 * 64];   // [key][d] ^((key&7)<<3)
    __shared__ __align__(16) ushort VThi[64 * 64], VTlo[64 * 64]; // [d][key] ^((d&7)<<3)
    __shared__ __align__(16) ushort Phi_s[8][16 * 64];            // per-wave [q][key] ^((q&7)<<3)
    __shared__ __align__(16) ushort Plo_s[8][16 * 64];

    const int t    = threadIdx.x;
    const int lane = t & 63;
    const int wv   = t >> 6;                   // wave 0..7 -> q rows wv*16..+15
    const int l15  = lane & 15;
    const int g2   = lane >> 4;                // 0..3

    const int L    = blockIdx.x;               // 384 blocks
    const int xcd  = L & 7;
    const int slot = L >> 3;                   // 0..47
    const int bh   = xcd * 3 + (slot >> 4);    // 0..23
    const int qb   = slot & 15;                // 0..15
    const int b    = bh / NHEAD;
    const int h    = bh % NHEAD;
    const int i0   = qb * 128;
    const int i    = i0 + wv * 16 + l15;       // this lane's q row (acc column)
    const int wv_lo = i0 + wv * 16;            // wave's first q row

    const float* kbase = &K[(size_t)bh * SEQ * HDIM];
    const float* vbase = &V[(size_t)bh * SEQ * HDIM];

    // ---- Q fragments (B-operand), hoisted, hi/lo via cvt_pk ----
    short8 qh[2], qlo[2];
    {
        const float* qrow = &Q[((size_t)bh * SEQ + i) * HDIM];
#pragma unroll
        for (int s = 0; s < 2; ++s) {
            float4 a = *(const float4*)&qrow[s * 32 + g2 * 8];
            float4 c = *(const float4*)&qrow[s * 32 + g2 * 8 + 4];
            S8U4 H, L;
            bf16_split2(a.x, a.y, H.u.x, L.u.x);
            bf16_split2(a.z, a.w, H.u.y, L.u.y);
            bf16_split2(c.x, c.y, H.u.z, L.u.z);
            bf16_split2(c.z, c.w, H.u.w, L.u.w);
            qh[s]  = H.s;
            qlo[s] = L.s;
        }
    }

    // ---- staging assignment (512 threads; 8 K-floats + 8 V-floats each) ----
    const int krow = t >> 3;                   // 0..63 (key row)
    const int kc   = (t & 7) * 8;              // d offset, 8 floats
    const int vkp  = t >> 4;                   // 0..31 -> keys 2vkp, 2vkp+1
    const int vdc  = (t & 15) * 4;             // d offset, 4 floats
    float4 kpre[2], vp0, vp1;

    const int jlo_blk = max(0, i0 - WIN);
    const int jhi_blk = min(SEQ - 1, i0 + 127 + WIN);

    auto LOADT = [&](int jt2) {
        const float* kr = &kbase[(size_t)(jt2 + krow) * HDIM + kc];
        kpre[0] = *(const float4*)&kr[0];
        kpre[1] = *(const float4*)&kr[4];
        vp0 = *(const float4*)&vbase[(size_t)(jt2 + 2 * vkp) * HDIM + vdc];
        vp1 = *(const float4*)&vbase[(size_t)(jt2 + 2 * vkp + 1) * HDIM + vdc];
    };
    auto STORET = [&]() {
#pragma unroll
        for (int c = 0; c < 2; ++c) {
            uint h01, l01, h23, l23;
            bf16_split2(kpre[c].x, kpre[c].y, h01, l01);
            bf16_split2(kpre[c].z, kpre[c].w, h23, l23);
            int idx = (krow * 64 + kc + c * 4) ^ ((krow & 7) << 3);
            *(uint2*)&Khi[idx] = make_uint2(h01, h23);
            *(uint2*)&Klo[idx] = make_uint2(l01, l23);
        }
        float va[4] = {vp0.x, vp0.y, vp0.z, vp0.w};
        float vb4[4] = {vp1.x, vp1.y, vp1.z, vp1.w};
#pragma unroll
        for (int j = 0; j < 4; ++j) {
            int d = vdc + j;
            uint hj, lj;
            bf16_split2(va[j], vb4[j], hj, lj);   // key 2vkp low, 2vkp+1 high
            int idx = (d * 64 + 2 * vkp) ^ ((d & 7) << 3);
            *(uint*)&VThi[idx] = hj;
            *(uint*)&VTlo[idx] = lj;
        }
    };

    float mrun = 0.f, lrun = 0.f;              // mask zeros always in softmax set
    f32x4 ctx[4];
#pragma unroll
    for (int f = 0; f < 4; ++f) ctx[f] = (f32x4){0.f, 0.f, 0.f, 0.f};

    LOADT(jlo_blk);
    STORET();                                   // preload tile 0

    for (int jt = jlo_blk; jt <= jhi_blk; jt += 64) {
        const bool more = (jt + 64) <= jhi_blk;
        if (more) LOADT(jt + 64);               // T14: issue early, write late
        __syncthreads();                        // staged tile visible

        // wave-uniform: does this tile intersect this wave's window?
        const bool active = (jt + 63 >= wv_lo - WIN) && (jt <= wv_lo + 15 + WIN);
        if (active) {
            // ---- QK^T: S^T[64 keys][16 q] ----
            f32x4 sacc[4];
#pragma unroll
            for (int f = 0; f < 4; ++f) sacc[f] = (f32x4){0.f, 0.f, 0.f, 0.f};
#pragma unroll
            for (int s = 0; s < 2; ++s) {
                short8 kh[4], kl[4];
#pragma unroll
                for (int f = 0; f < 4; ++f) {
                    int row = f * 16 + l15;
                    int idx = (row * 64 + s * 32 + g2 * 8) ^ ((row & 7) << 3);
                    kh[f] = *(const short8*)&Khi[idx];
                    kl[f] = *(const short8*)&Klo[idx];
                }
#pragma unroll
                for (int f = 0; f < 4; ++f) {
                    sacc[f] = __builtin_amdgcn_mfma_f32_16x16x32_bf16(kh[f], qh[s],  sacc[f], 0, 0, 0);
                    sacc[f] = __builtin_amdgcn_mfma_f32_16x16x32_bf16(kh[f], qlo[s], sacc[f], 0, 0, 0);
                    sacc[f] = __builtin_amdgcn_mfma_f32_16x16x32_bf16(kl[f], qh[s],  sacc[f], 0, 0, 0);
                }
            }

            // ---- softmax (lane-local rows; key j = jt + f*16 + g2*4 + r) ----
            float p[4][4];
            float tmax = -1e30f;
#pragma unroll
            for (int f = 0; f < 4; ++f)
#pragma unroll
                for (int r = 0; r < 4; ++r) {
                    int j = jt + f * 16 + g2 * 4 + r;
                    bool inw = (j >= i - WIN) && (j <= i + WIN);
                    float sv_ = inw ? sacc[f][r] : -1e30f;
                    p[f][r] = sv_;
                    tmax = fmaxf(tmax, sv_);
                }
            tmax = fmaxf(tmax, __shfl_xor(tmax, 16));
            tmax = fmaxf(tmax, __shfl_xor(tmax, 32));
            float m_new = fmaxf(mrun, tmax);
            float resc  = __expf(mrun - m_new);
            float lsum  = 0.f;
#pragma unroll
            for (int f = 0; f < 4; ++f)
#pragma unroll
                for (int r = 0; r < 4; ++r) {
                    float pe = __expf(p[f][r] - m_new);
                    p[f][r] = pe;
                    lsum += pe;
                }
            lsum += __shfl_xor(lsum, 16);
            lsum += __shfl_xor(lsum, 32);
            lrun = lrun * resc + lsum;
            mrun = m_new;
#pragma unroll
            for (int f = 0; f < 4; ++f) {
                ctx[f][0] *= resc; ctx[f][1] *= resc;
                ctx[f][2] *= resc; ctx[f][3] *= resc;
            }

            // ---- P -> bf16 hi/lo into per-wave LDS ([q][key], swizzled) ----
#pragma unroll
            for (int f = 0; f < 4; ++f) {
                uint h01, l01, h23, l23;
                bf16_split2(p[f][0], p[f][1], h01, l01);
                bf16_split2(p[f][2], p[f][3], h23, l23);
                int idx = (l15 * 64 + f * 16 + g2 * 4) ^ ((l15 & 7) << 3);
                *(uint2*)&Phi_s[wv][idx] = make_uint2(h01, h23);
                *(uint2*)&Plo_s[wv][idx] = make_uint2(l01, l23);
            }

            // ---- PV: ctx^T[64 d][16 q] += V^T . P^T ----
#pragma unroll
            for (int s = 0; s < 2; ++s) {
                int pidx = (l15 * 64 + s * 32 + g2 * 8) ^ ((l15 & 7) << 3);
                short8 ph = *(const short8*)&Phi_s[wv][pidx];
                short8 pl = *(const short8*)&Plo_s[wv][pidx];
#pragma unroll
                for (int f = 0; f < 4; ++f) {
                    int row = f * 16 + l15;
                    int idx = (row * 64 + s * 32 + g2 * 8) ^ ((row & 7) << 3);
                    short8 vh = *(const short8*)&VThi[idx];
                    short8 vl = *(const short8*)&VTlo[idx];
                    ctx[f] = __builtin_amdgcn_mfma_f32_16x16x32_bf16(vh, ph, ctx[f], 0, 0, 0);
                    ctx[f] = __builtin_amdgcn_mfma_f32_16x16x32_bf16(vl, ph, ctx[f], 0, 0, 0);
                    ctx[f] = __builtin_amdgcn_mfma_f32_16x16x32_bf16(vh, pl, ctx[f], 0, 0, 0);
                }
            }
        }

        __syncthreads();                        // all reads of this tile done
        if (more) STORET();                     // commit prefetched tile
    }

    // ---- out-of-window correction + normalize + store ----
    const int jlo = max(0, i - WIN);
    const int jhi = min(SEQ - 1, i + WIN);
    const int cnt = jhi - jlo + 1;
    const float em   = __expf(-mrun);
    const float ltot = lrun + (float)(SEQ - cnt) * em;
    const float inv  = 1.f / ltot;

    const float* vpT = &Vpre[((size_t)bh * SEQ + (SEQ - 1)) * HDIM];
    const float* vpH = &Vpre[((size_t)bh * SEQ + jhi) * HDIM];
    const float* vpL = &Vpre[((size_t)bh * SEQ + (jlo - 1)) * HDIM];  // read only if jlo>0
    float* orow = &out[((size_t)(b * SEQ + i)) * HIDDEN + h * HDIM];

#pragma unroll
    for (int f = 0; f < 4; ++f) {
        int d0 = f * 16 + g2 * 4;
        float4 tt = *(const float4*)&vpT[d0];
        float4 hh = *(const float4*)&vpH[d0];
        float4 ll = {0.f, 0.f, 0.f, 0.f};
        if (jlo > 0) ll = *(const float4*)&vpL[d0];
        float4 o;
        o.x = (ctx[f][0] + em * (tt.x - hh.x + ll.x)) * inv;
        o.y = (ctx[f][1] + em * (tt.y - hh.y + ll.y)) * inv;
        o.z = (ctx[f][2] + em * (tt.z - hh.z + ll.z)) * inv;
        o.w = (ctx[f][3] + em * (tt.w - hh.w + ll.w)) * inv;
        *(float4*)&orow[d0] = o;
    }
}

// ---------------------------------------------------------------------------
extern "C" void kernel_launch(void* const* d_in, const int* in_sizes, int n_in,
                              void* d_out, int out_size, void* d_ws, size_t ws_size,
                              hipStream_t stream) {
    const float* X  = (const float*)d_in[0];
    const float* Wq = (const float*)d_in[1];
    const float* bq = (const float*)d_in[2];
    const float* Wk = (const float*)d_in[3];
    const float* bk = (const float*)d_in[4];
    const float* Wv = (const float*)d_in[5];
    const float* bv = (const float*)d_in[6];
    float* out = (float*)d_out;

    const size_t TEN = (size_t)BATCH * NHEAD * SEQ * HDIM;  // 3,145,728 floats
    float* qf   = (float*)d_ws;
    float* kf   = qf + TEN;
    float* vf   = kf + TEN;
    float* vpre = vf + TEN;   // 50.3 MB of ws total

    proj_mfma_kernel<<<dim3(MTOT / 128, NHEAD, 3), 256, 0, stream>>>(
        X, Wq, bq, Wk, bk, Wv, bv, qf, kf, vf);
    vprefix_kernel<<<dim3(BATCH * NHEAD), 1024, 0, stream>>>(vf, vpre);
    attn_kernel<<<dim3((SEQ / 128) * BATCH * NHEAD), 512, 0, stream>>>(
        qf, kf, vf, vpre, out);
}